// Round 18
// baseline (145.155 us; speedup 1.0000x reference)
//
#include <hip/hip_runtime.h>
#include <math.h>

#define N_PTS 8192
#define KNN 16

typedef __attribute__((ext_vector_type(8))) short bf16x8;
typedef __attribute__((ext_vector_type(4))) float f32x4v;

__device__ __forceinline__ unsigned short f2bf(float f)
{
    unsigned u = __float_as_uint(f);
    u = u + 0x7fffu + ((u >> 16) & 1u);       // round-to-nearest-even
    return (unsigned short)(u >> 16);
}
__device__ __forceinline__ unsigned pack2(float a, float b)
{
    return (unsigned)f2bf(a) | ((unsigned)f2bf(b) << 16);
}
__device__ __forceinline__ float bf2f(unsigned short h)
{
    return __uint_as_float((unsigned)h << 16);
}
__device__ __forceinline__ float rfl(float x)   // force block-uniform value to SGPR
{
    return __int_as_float(__builtin_amdgcn_readfirstlane(__float_as_int(x)));
}

// ---------------------------------------------------------------------------
// prep_all (unchanged from passing R16): Wb frags | pos4 | v1.
// ---------------------------------------------------------------------------
__global__ __launch_bounds__(256) void prep_all(
    const float* __restrict__ pos, float4* __restrict__ pos4,
    unsigned short* __restrict__ v1,
    const float* __restrict__ w1a, const float* __restrict__ b1a,
    const float* __restrict__ w1b, const float* __restrict__ w2b,
    const float* __restrict__ w3b,
    uint4* __restrict__ dst)
{
    const int b = blockIdx.x;
    if (b < 48) {
        if (threadIdx.x >= 64) return;
        const float* Ws[3] = {w1b, w2b, w3b};
        const int Nd[3] = {64, 64, 128};
        const int start[4] = {0, 8, 16, 48};
        int m = 0;
        while (b >= start[m + 1]) ++m;
        const int f  = b - start[m];
        const int NT = Nd[m] / 16;
        const int ks = f / NT, nt = f % NT;
        const int lane = threadIdx.x;
        const int c  = nt * 16 + (lane & 15);
        const int k0 = ks * 32 + (lane >> 4) * 8;
        const int N = Nd[m];
        const float* W = Ws[m];
        float v[8];
#pragma unroll
        for (int j = 0; j < 8; ++j) v[j] = W[(k0 + j) * N + c];
        uint4 o;
        o.x = pack2(v[0], v[1]); o.y = pack2(v[2], v[3]);
        o.z = pack2(v[4], v[5]); o.w = pack2(v[6], v[7]);
        dst[b * 64 + lane] = o;
    } else if (b < 80) {
        const int i = (b - 48) * 256 + threadIdx.x;
        const float x = pos[i * 3 + 0];
        const float y = pos[i * 3 + 1];
        const float z = pos[i * 3 + 2];
        pos4[i] = make_float4(x, y, z, fmaf(x, x, fmaf(y, y, z * z)));
    } else {
        const int i = (b - 80) * 256 + threadIdx.x;
        const float px = pos[i * 3 + 0], py = pos[i * 3 + 1], pz = pos[i * 3 + 2];
#pragma unroll
        for (int c8 = 0; c8 < 64; c8 += 8) {
            unsigned o[4];
#pragma unroll
            for (int d2 = 0; d2 < 4; ++d2) {
                float r[2];
#pragma unroll
                for (int e = 0; e < 2; ++e) {
                    const int c = c8 + d2 * 2 + e;
                    float acc = b1a[c];
                    acc = fmaf(px, w1a[0 * 64 + c] + w1a[3 * 64 + c], acc);
                    acc = fmaf(py, w1a[1 * 64 + c] + w1a[4 * 64 + c], acc);
                    acc = fmaf(pz, w1a[2 * 64 + c] + w1a[5 * 64 + c], acc);
                    r[e] = acc;
                }
                o[d2] = pack2(r[0], r[1]);
            }
            *reinterpret_cast<uint4*>(v1 + i * 64 + c8) = make_uint4(o[0], o[1], o[2], o[3]);
        }
    }
}

// ---------------------------------------------------------------------------
// kNN threshold-select, 16-wave block edition.
// Block = 1024 threads (16 waves), QB=16 queries (SGPR, pre-scaled by -2).
// Grid 512 = 2 blocks/CU x 16 waves = 32 waves/CU (100% occupancy).
// Each wave scans its private 512-candidate chunk in 8 windows of 64,
// staged via global_load_lds into 3 rotating 16 KB buffers (wave-private
// slots tile[b][w*64+lane]) -> no cross-thread sharing -> barrier-free scan.
// Lookahead-2: issue stage(t+2), s_waitcnt vmcnt(2) (t done; t+1,t+2 in
// flight), sched_barrier(0), consume t. j = w*512 + t*64 + lane keeps
// j%64 == lane: T = 16th smallest of the 64 column minima >= true 16th
// distance (16 smallest column minima are distinct points). Cross-wave fold
// via LDS atomicMin on u32 sortkeys (monotone bijection -> T bit-identical).
// Pass 2: branchless hit-mask collects s <= T (exact f32, exp ~25, CAP=128);
// exact top-16 via LDS rank-select on unique keys (sortkey(s)<<32 | j),
// ties by lowest index. 1 query per wave in selection phases.
// ---------------------------------------------------------------------------
__device__ __forceinline__ unsigned sortkey(const float d2)
{
    unsigned u = __float_as_uint(d2);
    u ^= (unsigned)((int)u >> 31) | 0x80000000u;
    return u;
}
__device__ __forceinline__ float unkey(unsigned k)
{
    const unsigned u = (k & 0x80000000u) ? (k ^ 0x80000000u) : ~k;
    return __uint_as_float(u);
}

constexpr int CAP   = 128;
constexpr int QB    = 16;
constexpr int NWAVE = 16;                  // waves per block
constexpr int CHUNK = N_PTS / NWAVE;       // 512 candidates per wave
constexpr int NWIN  = CHUNK / 64;          // 8 windows per wave per pass

__device__ __forceinline__ void stage_tile(const float4* src, float4* dst)
{
    __builtin_amdgcn_global_load_lds(
        (const __attribute__((address_space(1))) void*)src,
        (__attribute__((address_space(3))) void*)dst, 16, 0, 0);
}

__global__ __launch_bounds__(1024, 8) void knn_kernel(const float4* __restrict__ pos4,
                                                      int* __restrict__ idx_out)
{
    __shared__ float4 tile[3][NWAVE * 64];           // 48 KB
    __shared__ unsigned minkey[QB][64];              // 4 KB
    __shared__ float Ts[QB];
    __shared__ unsigned long long surv[QB][CAP];     // 16 KB
    __shared__ int scnt[QB];

    const int tid   = threadIdx.x;
    const int w     = tid >> 6;
    const int lane  = tid & 63;
    const int qbase = blockIdx.x * QB;

    if (tid < QB) scnt[tid] = 0;
    reinterpret_cast<unsigned*>(minkey)[tid] = 0xFFFFFFFFu;   // 1024 entries

    float qx[QB], qy[QB], qz[QB];
#pragma unroll
    for (int qi = 0; qi < QB; ++qi) {
        const float4 qp = pos4[qbase + qi];
        qx[qi] = rfl(-2.0f * qp.x);
        qy[qi] = rfl(-2.0f * qp.y);
        qz[qi] = rfl(-2.0f * qp.z);
    }

    const float4* src = pos4 + w * CHUNK + lane;   // this thread's stage source

    float mn[QB];
#pragma unroll
    for (int qi = 0; qi < QB; ++qi) mn[qi] = 1e30f;

    // ---- pass 1: per-lane min of s; 3-buffer lookahead-2, barrier-free ----
    stage_tile(src + 0 * 64, &tile[0][w * 64]);
    stage_tile(src + 1 * 64, &tile[1][w * 64]);
    __syncthreads();   // orders scnt/minkey init before end-of-pass atomics
#pragma unroll 1
    for (int t = 0; t < NWIN; ++t) {
        if (t + 2 < NWIN) {
            stage_tile(src + (t + 2) * 64, &tile[(t + 2) % 3][w * 64]);
            asm volatile("s_waitcnt vmcnt(2)" ::: "memory");  // t done; t+1,t+2 in flight
        } else if (t + 2 == NWIN) {
            asm volatile("s_waitcnt vmcnt(1)" ::: "memory");
        } else {
            asm volatile("s_waitcnt vmcnt(0)" ::: "memory");
        }
        __builtin_amdgcn_sched_barrier(0);
        const float4 p = tile[t % 3][w * 64 + lane];
#pragma unroll
        for (int qi = 0; qi < QB; ++qi) {
            const float s = fmaf(qx[qi], p.x, fmaf(qy[qi], p.y, fmaf(qz[qi], p.z, p.w)));
            mn[qi] = fminf(mn[qi], s);
        }
    }
#pragma unroll
    for (int qi = 0; qi < QB; ++qi) atomicMin(&minkey[qi][lane], sortkey(mn[qi]));
    __syncthreads();

    // ---- T per query: wave w sorts query w (u32 bitonic over 64 lanes) ----
    {
        unsigned v = minkey[w][lane];
#pragma unroll
        for (int kk = 2; kk <= 64; kk <<= 1)
#pragma unroll
            for (int j = kk >> 1; j > 0; j >>= 1) {
                const unsigned o = __shfl_xor(v, j);
                const bool up = ((lane & kk) == 0);
                const bool lo = ((lane & j) == 0);
                v = (up == lo) ? min(v, o) : max(v, o);
            }
        if (lane == 15) Ts[w] = unkey(v);
    }
    __syncthreads();

    float T[QB];
#pragma unroll
    for (int qi = 0; qi < QB; ++qi) T[qi] = rfl(Ts[qi]);

    // ---- pass 2: collect survivors (same pipeline, branchless hit-mask) ----
    stage_tile(src + 0 * 64, &tile[0][w * 64]);
    stage_tile(src + 1 * 64, &tile[1][w * 64]);
#pragma unroll 1
    for (int t = 0; t < NWIN; ++t) {
        if (t + 2 < NWIN) {
            stage_tile(src + (t + 2) * 64, &tile[(t + 2) % 3][w * 64]);
            asm volatile("s_waitcnt vmcnt(2)" ::: "memory");
        } else if (t + 2 == NWIN) {
            asm volatile("s_waitcnt vmcnt(1)" ::: "memory");
        } else {
            asm volatile("s_waitcnt vmcnt(0)" ::: "memory");
        }
        __builtin_amdgcn_sched_barrier(0);
        const float4 p = tile[t % 3][w * 64 + lane];
        const int j = w * CHUNK + t * 64 + lane;
        float s[QB];
        bool hit = false;
#pragma unroll
        for (int qi = 0; qi < QB; ++qi) {
            s[qi] = fmaf(qx[qi], p.x, fmaf(qy[qi], p.y, fmaf(qz[qi], p.z, p.w)));
            hit = hit | (s[qi] <= T[qi]);
        }
        if (__builtin_expect(hit, 0)) {
#pragma unroll
            for (int qi = 0; qi < QB; ++qi)
                if (s[qi] <= T[qi]) {
                    const int slot = atomicAdd(&scnt[qi], 1);
                    if (slot < CAP)
                        surv[qi][slot] = ((unsigned long long)sortkey(s[qi]) << 32) | (unsigned)j;
                }
        }
    }
    __syncthreads();

    // ---- exact top-16: wave w ranks query w (rank = #{key < mine}) ----
    {
        const int q = w;
        const int n = min(scnt[q], CAP);
        const unsigned long long k0 = (lane < n) ? surv[q][lane] : ~0ull;
        const unsigned long long k1 = (lane + 64 < n) ? surv[q][lane + 64] : ~0ull;
        int r0 = 0, r1 = 0;
#pragma unroll 4
        for (int e = 0; e < n; ++e) {
            const unsigned long long ke = surv[q][e];   // LDS broadcast read
            r0 += (ke < k0) ? 1 : 0;
            r1 += (ke < k1) ? 1 : 0;
        }
        if (lane < n && r0 < KNN)
            idx_out[(qbase + q) * KNN + r0] = (int)(unsigned)(k0 & 0xFFFFFFFFu);
        if (lane + 64 < n && r1 < KNN)
            idx_out[(qbase + q) * KNN + r1] = (int)(unsigned)(k1 & 0xFFFFFFFFu);
    }
}

// ---------------------------------------------------------------------------
// conv_fused (unchanged from passing R16): h_ij = relu(v_j - u_i);
// GEMM2 MFMA + max-aggregate + relu; VNEXT epilogue computes next layer's v.
// ---------------------------------------------------------------------------
template <int CMID, int COUT, int WM, int WN, int VNEXT>
__global__ __launch_bounds__(256) void conv_fused(
    const unsigned short* __restrict__ v, const float* __restrict__ pos,
    const int* __restrict__ idx,
    const float* __restrict__ WaRel,            // 3 x CMID (rows CIN..CIN+2 of Wa)
    const uint4* __restrict__ fB, const float* __restrict__ bb,
    const float* __restrict__ Wnext, const float* __restrict__ bnext,
    float* __restrict__ out, unsigned short* __restrict__ vout)
{
    constexpr int PB  = 8, M = 128;
    constexpr int KP2 = CMID + 8;
    constexpr int KS2 = CMID / 32;
    constexpr int NT  = COUT / 16;
    constexpr int NTW = NT / WN;
    constexpr int MFW = (M / 16) / WM;

    __shared__ int nbr[M];
    __shared__ float ubuf[PB][CMID];
    __shared__ __align__(16) unsigned short hbuf[M * KP2];

    const int tid  = threadIdx.x;
    const int lane = tid & 63;
    const int w    = tid >> 6;
    const int wm   = w / WN, wn = w % WN;
    const int i0   = blockIdx.x * PB;

    if (tid < M) nbr[tid] = idx[i0 * KNN + tid];
    for (int e = tid; e < PB * CMID; e += 256) {
        const int pt = e / CMID, c = e % CMID;
        float u = pos[(i0 + pt) * 3 + 0] * WaRel[c];
        u = fmaf(pos[(i0 + pt) * 3 + 1], WaRel[CMID + c], u);
        u = fmaf(pos[(i0 + pt) * 3 + 2], WaRel[2 * CMID + c], u);
        ubuf[pt][c] = u;
    }
    __syncthreads();

    {
        const int row = tid >> 1, hh = tid & 1;
        const int j = nbr[row], pt = row >> 4;
        const int cb = hh * (CMID / 2);
#pragma unroll
        for (int cc = 0; cc < CMID / 2; cc += 8) {
            const uint4 vv = *reinterpret_cast<const uint4*>(v + j * CMID + cb + cc);
            const unsigned dw[4] = {vv.x, vv.y, vv.z, vv.w};
            unsigned o[4];
#pragma unroll
            for (int d2 = 0; d2 < 4; ++d2) {
                const int c = cb + cc + d2 * 2;
                const float flo = __uint_as_float(dw[d2] << 16);
                const float fhi = __uint_as_float(dw[d2] & 0xffff0000u);
                const float rlo = fmaxf(flo - ubuf[pt][c],     0.0f);
                const float rhi = fmaxf(fhi - ubuf[pt][c + 1], 0.0f);
                o[d2] = pack2(rlo, rhi);
            }
            *reinterpret_cast<uint4*>(&hbuf[row * KP2 + cb + cc]) =
                make_uint4(o[0], o[1], o[2], o[3]);
        }
    }
    __syncthreads();

    float outv[MFW][NTW];
    {
        uint4 b2[KS2][NTW];
#pragma unroll
        for (int ks = 0; ks < KS2; ++ks)
#pragma unroll
            for (int nt = 0; nt < NTW; ++nt)
                b2[ks][nt] = fB[(ks * NT + wn * NTW + nt) * 64 + lane];

        f32x4v acc2[MFW][NTW];
#pragma unroll
        for (int mf = 0; mf < MFW; ++mf)
#pragma unroll
            for (int nt = 0; nt < NTW; ++nt) acc2[mf][nt] = (f32x4v)0.0f;

#pragma unroll
        for (int mf = 0; mf < MFW; ++mf) {
            bf16x8 a[KS2];
#pragma unroll
            for (int ks = 0; ks < KS2; ++ks)
                a[ks] = *reinterpret_cast<const bf16x8*>(
                    &hbuf[((wm * MFW + mf) * 16 + (lane & 15)) * KP2 + ks * 32 + (lane >> 4) * 8]);
#pragma unroll
            for (int nt = 0; nt < NTW; ++nt)
#pragma unroll
                for (int ks = 0; ks < KS2; ++ks)
                    acc2[mf][nt] = __builtin_amdgcn_mfma_f32_16x16x32_bf16(
                        a[ks], __builtin_bit_cast(bf16x8, b2[ks][nt]), acc2[mf][nt], 0, 0, 0);
        }

        float bbv[NTW];
#pragma unroll
        for (int nt = 0; nt < NTW; ++nt) bbv[nt] = bb[(wn * NTW + nt) * 16 + (lane & 15)];

#pragma unroll
        for (int mf = 0; mf < MFW; ++mf)
#pragma unroll
            for (int nt = 0; nt < NTW; ++nt) {
                const f32x4v t = acc2[mf][nt];
                float m0 = fmaxf(fmaxf(t[0], t[1]), fmaxf(t[2], t[3]));
                m0 = fmaxf(m0, __shfl_xor(m0, 16));
                m0 = fmaxf(m0, __shfl_xor(m0, 32));
                outv[mf][nt] = fmaxf(m0 + bbv[nt], 0.0f);
            }
    }
    __syncthreads();

#pragma unroll
    for (int mf = 0; mf < MFW; ++mf)
#pragma unroll
        for (int nt = 0; nt < NTW; ++nt) {
            if (lane < 16) {
                const int pt = wm * MFW + mf;
                const int c  = (wn * NTW + nt) * 16 + lane;
                out[(i0 + pt) * COUT + c] = outv[mf][nt];
                if constexpr (VNEXT > 0) hbuf[pt * KP2 + c] = f2bf(outv[mf][nt]);
            }
        }

    if constexpr (VNEXT > 0) {
        __syncthreads();
        constexpr int CPT = VNEXT / 32;
        const int pt = tid >> 5;
        const int c0 = (tid & 31) * CPT;
        float acc[CPT];
#pragma unroll
        for (int e = 0; e < CPT; ++e) acc[e] = bnext[c0 + e];
        for (int k = 0; k < COUT; ++k) {
            const float hk = bf2f(hbuf[pt * KP2 + k]);
#pragma unroll
            for (int e = 0; e < CPT; ++e)
                acc[e] = fmaf(hk, Wnext[k * VNEXT + c0 + e], acc[e]);
        }
#pragma unroll
        for (int d = 0; d < 3; ++d) {
            const float pd = pos[(i0 + pt) * 3 + d];
#pragma unroll
            for (int e = 0; e < CPT; ++e)
                acc[e] = fmaf(pd, Wnext[(COUT + d) * VNEXT + c0 + e], acc[e]);
        }
        if constexpr (CPT == 2) {
            *reinterpret_cast<unsigned*>(vout + (i0 + pt) * VNEXT + c0) = pack2(acc[0], acc[1]);
        } else {
            uint2 o;
            o.x = pack2(acc[0], acc[1]);
            o.y = pack2(acc[2], acc[3]);
            *reinterpret_cast<uint2*>(vout + (i0 + pt) * VNEXT + c0) = o;
        }
    }
}

extern "C" void kernel_launch(void* const* d_in, const int* in_sizes, int n_in,
                              void* d_out, int out_size, void* d_ws, size_t ws_size,
                              hipStream_t stream)
{
    const float* pos = (const float*)d_in[0];
    const float* W1a = (const float*)d_in[1];
    const float* b1a = (const float*)d_in[2];
    const float* W1b = (const float*)d_in[3];
    const float* b1b = (const float*)d_in[4];
    const float* W2a = (const float*)d_in[5];
    const float* b2a = (const float*)d_in[6];
    const float* W2b = (const float*)d_in[7];
    const float* b2b = (const float*)d_in[8];
    const float* W3a = (const float*)d_in[9];
    const float* b3a = (const float*)d_in[10];
    const float* W3b = (const float*)d_in[11];
    const float* b3b = (const float*)d_in[12];

    float* out = (float*)d_out;
    float* h1 = out;                        // 8192 x 64
    float* h2 = out + N_PTS * 64;           // 8192 x 64
    float* h3 = out + N_PTS * 128;          // 8192 x 128

    // workspace: idx (512K) | Wb frags (48K) | v3 (2MB bf16)
    int*            idx     = (int*)d_ws;
    uint4*          wsFrags = (uint4*)((char*)d_ws + 524288);
    unsigned short* v3      = (unsigned short*)((char*)d_ws + 589824);

    // h3 region (dead until conv3): pos4 (128K) | v1 (1MB) | v2 (1MB)
    float4*         pos4 = (float4*)h3;
    unsigned short* v1   = (unsigned short*)((char*)h3 + 131072);
    unsigned short* v2   = (unsigned short*)((char*)h3 + 1179648);

    prep_all<<<112, 256, 0, stream>>>(pos, pos4, v1, W1a, b1a, W1b, W2b, W3b, wsFrags);
    knn_kernel<<<N_PTS / QB, 1024, 0, stream>>>(pos4, idx);

    const uint4* fW1b = wsFrags + 0 * 64;
    const uint4* fW2b = wsFrags + 8 * 64;
    const uint4* fW3b = wsFrags + 16 * 64;

    conv_fused<64, 64, 4, 1, 64><<<N_PTS / 8, 256, 0, stream>>>(
        v1, pos, idx, W1a + 3 * 64, fW1b, b1b, W2a, b2a, h1, v2);
    conv_fused<64, 64, 4, 1, 128><<<N_PTS / 8, 256, 0, stream>>>(
        v2, pos, idx, W2a + 64 * 64, fW2b, b2b, W3a, b3a, h2, v3);
    conv_fused<128, 128, 2, 2, 0><<<N_PTS / 8, 256, 0, stream>>>(
        v3, pos, idx, W3a + 64 * 128, fW3b, b3b, nullptr, nullptr, h3, nullptr);
}

// Round 19
// 99.982 us; speedup vs baseline: 1.4518x; 1.4518x over previous
//
#include <hip/hip_runtime.h>
#include <math.h>

#define N_PTS 8192
#define KNN 16

typedef __attribute__((ext_vector_type(8))) short bf16x8;
typedef __attribute__((ext_vector_type(4))) float f32x4v;

__device__ __forceinline__ unsigned short f2bf(float f)
{
    unsigned u = __float_as_uint(f);
    u = u + 0x7fffu + ((u >> 16) & 1u);       // round-to-nearest-even
    return (unsigned short)(u >> 16);
}
__device__ __forceinline__ unsigned pack2(float a, float b)
{
    return (unsigned)f2bf(a) | ((unsigned)f2bf(b) << 16);
}
__device__ __forceinline__ float bf2f(unsigned short h)
{
    return __uint_as_float((unsigned)h << 16);
}
__device__ __forceinline__ float rfl(float x)   // force block-uniform value to SGPR
{
    return __int_as_float(__builtin_amdgcn_readfirstlane(__float_as_int(x)));
}

// ---------------------------------------------------------------------------
// prep_all (unchanged from passing R16): Wb frags | pos4 | v1.
// ---------------------------------------------------------------------------
__global__ __launch_bounds__(256) void prep_all(
    const float* __restrict__ pos, float4* __restrict__ pos4,
    unsigned short* __restrict__ v1,
    const float* __restrict__ w1a, const float* __restrict__ b1a,
    const float* __restrict__ w1b, const float* __restrict__ w2b,
    const float* __restrict__ w3b,
    uint4* __restrict__ dst)
{
    const int b = blockIdx.x;
    if (b < 48) {
        if (threadIdx.x >= 64) return;
        const float* Ws[3] = {w1b, w2b, w3b};
        const int Nd[3] = {64, 64, 128};
        const int start[4] = {0, 8, 16, 48};
        int m = 0;
        while (b >= start[m + 1]) ++m;
        const int f  = b - start[m];
        const int NT = Nd[m] / 16;
        const int ks = f / NT, nt = f % NT;
        const int lane = threadIdx.x;
        const int c  = nt * 16 + (lane & 15);
        const int k0 = ks * 32 + (lane >> 4) * 8;
        const int N = Nd[m];
        const float* W = Ws[m];
        float v[8];
#pragma unroll
        for (int j = 0; j < 8; ++j) v[j] = W[(k0 + j) * N + c];
        uint4 o;
        o.x = pack2(v[0], v[1]); o.y = pack2(v[2], v[3]);
        o.z = pack2(v[4], v[5]); o.w = pack2(v[6], v[7]);
        dst[b * 64 + lane] = o;
    } else if (b < 80) {
        const int i = (b - 48) * 256 + threadIdx.x;
        const float x = pos[i * 3 + 0];
        const float y = pos[i * 3 + 1];
        const float z = pos[i * 3 + 2];
        pos4[i] = make_float4(x, y, z, fmaf(x, x, fmaf(y, y, z * z)));
    } else {
        const int i = (b - 80) * 256 + threadIdx.x;
        const float px = pos[i * 3 + 0], py = pos[i * 3 + 1], pz = pos[i * 3 + 2];
#pragma unroll
        for (int c8 = 0; c8 < 64; c8 += 8) {
            unsigned o[4];
#pragma unroll
            for (int d2 = 0; d2 < 4; ++d2) {
                float r[2];
#pragma unroll
                for (int e = 0; e < 2; ++e) {
                    const int c = c8 + d2 * 2 + e;
                    float acc = b1a[c];
                    acc = fmaf(px, w1a[0 * 64 + c] + w1a[3 * 64 + c], acc);
                    acc = fmaf(py, w1a[1 * 64 + c] + w1a[4 * 64 + c], acc);
                    acc = fmaf(pz, w1a[2 * 64 + c] + w1a[5 * 64 + c], acc);
                    r[e] = acc;
                }
                o[d2] = pack2(r[0], r[1]);
            }
            *reinterpret_cast<uint4*>(v1 + i * 64 + c8) = make_uint4(o[0], o[1], o[2], o[3]);
        }
    }
}

// ---------------------------------------------------------------------------
// kNN via MFMA. Block = 512 threads (8 waves), 16 queries (one MFMA q-tile).
// s~[q][j] = -2 q.p_j + |p_j|^2 computed as A(16x32) x B(32x8192) with
// A[q][0..3] = (-2qx,-2qy,-2qz,1), B[0..3][j] = (px,py,pz,|p|^2), bf16.
// One mfma_f32_16x16x32_bf16 per 16-cand tile: acc[r] = s~ for query
// row=(lane>>4)*4+r, cand col=lane&15 (verified layout from conv GEMM).
// Wave w sweeps cands [w*1024,(w+1)*1024) in 16 groups of 64 (4 tiles),
// staged via global_load_lds, 3 buffers, lookahead-2, barrier-free.
// Threshold: class (w, lane&15) = 64 cands; 128 classes folded to 64 ->
// 16th smallest of 64 folded minima (distinct points) >= true 16th s~;
// + per-query margin EPS(q)=0.016(|q|^2+2) >= 2*eps_bf16 -> superset valid.
// Pass 2 collects s~ <= T+EPS (CAP=256); merge RESCORES survivors in exact
// f32 (same fmaf chain as all passing rounds) -> exact top-16, ties by idx.
// ---------------------------------------------------------------------------
__device__ __forceinline__ unsigned sortkey(const float d2)
{
    unsigned u = __float_as_uint(d2);
    u ^= (unsigned)((int)u >> 31) | 0x80000000u;
    return u;
}
__device__ __forceinline__ float unkey(unsigned k)
{
    const unsigned u = (k & 0x80000000u) ? (k ^ 0x80000000u) : ~k;
    return __uint_as_float(u);
}

constexpr int CAPM = 256;
constexpr int QB   = 16;
constexpr int NGRP = 16;     // groups of 64 cands per wave per pass

__device__ __forceinline__ void stage_tile(const float4* src, float4* dst)
{
    __builtin_amdgcn_global_load_lds(
        (const __attribute__((address_space(1))) void*)src,
        (__attribute__((address_space(3))) void*)dst, 16, 0, 0);
}

__global__ __launch_bounds__(512) void knn_kernel(const float4* __restrict__ pos4,
                                                  int* __restrict__ idx_out)
{
    __shared__ float4 tile[3][512];                    // 24 KB
    __shared__ unsigned minkey[QB][128];               // 8 KB
    __shared__ float Ts[QB];
    __shared__ unsigned surv[QB][CAPM];                // 16 KB
    __shared__ unsigned long long keybuf[8][CAPM];     // 16 KB
    __shared__ int scnt[QB];

    const int tid   = threadIdx.x;
    const int w     = tid >> 6;
    const int lane  = tid & 63;
    const int qbase = blockIdx.x * QB;

    if (tid < QB) scnt[tid] = 0;
#pragma unroll
    for (int s = 0; s < 4; ++s)
        (&minkey[0][0])[tid + s * 512] = 0xFFFFFFFFu;

    // ---- A-frag: lanes 0-15 hold query (lane&15): k=0..3 = (-2qx,-2qy,-2qz,1)
    bf16x8 afrag;
    {
        uint4 au = make_uint4(0, 0, 0, 0);
        if (lane < 16) {
            const float4 q = pos4[qbase + lane];
            au.x = pack2(-2.0f * q.x, -2.0f * q.y);
            au.y = pack2(-2.0f * q.z, 1.0f);
        }
        afrag = __builtin_bit_cast(bf16x8, au);
    }

    const float4* src = pos4 + w * 1024 + lane;   // stage source (+= g*64)

    float mn[4];
#pragma unroll
    for (int r = 0; r < 4; ++r) mn[r] = 1e30f;

    // ---- pass 1: per-(lane,r) class minima of s~; MFMA per 16-cand tile ----
    stage_tile(src + 0 * 64, &tile[0][w * 64]);
    stage_tile(src + 1 * 64, &tile[1][w * 64]);
    __syncthreads();   // orders scnt/minkey init
#pragma unroll 1
    for (int g = 0; g < NGRP; ++g) {
        if (g + 2 < NGRP) {
            stage_tile(src + (g + 2) * 64, &tile[(g + 2) % 3][w * 64]);
            asm volatile("s_waitcnt vmcnt(2)" ::: "memory");
        } else if (g + 2 == NGRP) {
            asm volatile("s_waitcnt vmcnt(1)" ::: "memory");
        } else {
            asm volatile("s_waitcnt vmcnt(0)" ::: "memory");
        }
        __builtin_amdgcn_sched_barrier(0);
#pragma unroll
        for (int tt = 0; tt < 4; ++tt) {
            const float4 p = tile[g % 3][w * 64 + tt * 16 + (lane & 15)];
            uint4 bu = make_uint4(0, 0, 0, 0);
            if (lane < 16) {
                bu.x = pack2(p.x, p.y);
                bu.y = pack2(p.z, p.w);
            }
            const f32x4v acc = __builtin_amdgcn_mfma_f32_16x16x32_bf16(
                afrag, __builtin_bit_cast(bf16x8, bu), (f32x4v)0.0f, 0, 0, 0);
#pragma unroll
            for (int r = 0; r < 4; ++r) mn[r] = fminf(mn[r], acc[r]);
        }
    }
    // class (w, lane&15) minima for query (lane>>4)*4+r — unique writer
#pragma unroll
    for (int r = 0; r < 4; ++r)
        minkey[(lane >> 4) * 4 + r][w * 16 + (lane & 15)] = sortkey(mn[r]);
    __syncthreads();

    // ---- T per query: wave w handles queries 2w, 2w+1 ----
#pragma unroll
    for (int k = 0; k < 2; ++k) {
        const int q = w * 2 + k;
        unsigned v = min(minkey[q][lane], minkey[q][lane + 64]);   // fold 128->64
#pragma unroll
        for (int kk = 2; kk <= 64; kk <<= 1)
#pragma unroll
            for (int j = kk >> 1; j > 0; j >>= 1) {
                const unsigned o = __shfl_xor(v, j);
                const bool up = ((lane & kk) == 0);
                const bool lo = ((lane & j) == 0);
                v = (up == lo) ? min(v, o) : max(v, o);
            }
        if (lane == 15) {
            const float4 qq = pos4[qbase + q];
            const float q2 = fmaf(qq.x, qq.x, fmaf(qq.y, qq.y, qq.z * qq.z));
            Ts[q] = unkey(v) + 0.016f * (q2 + 2.0f);   // margin >= 2*bf16 err
        }
    }
    __syncthreads();

    float Tr[4];
#pragma unroll
    for (int r = 0; r < 4; ++r) Tr[r] = Ts[(lane >> 4) * 4 + r];

    // ---- pass 2: collect survivors (s~ <= T+EPS) ----
    stage_tile(src + 0 * 64, &tile[0][w * 64]);
    stage_tile(src + 1 * 64, &tile[1][w * 64]);
#pragma unroll 1
    for (int g = 0; g < NGRP; ++g) {
        if (g + 2 < NGRP) {
            stage_tile(src + (g + 2) * 64, &tile[(g + 2) % 3][w * 64]);
            asm volatile("s_waitcnt vmcnt(2)" ::: "memory");
        } else if (g + 2 == NGRP) {
            asm volatile("s_waitcnt vmcnt(1)" ::: "memory");
        } else {
            asm volatile("s_waitcnt vmcnt(0)" ::: "memory");
        }
        __builtin_amdgcn_sched_barrier(0);
#pragma unroll
        for (int tt = 0; tt < 4; ++tt) {
            const float4 p = tile[g % 3][w * 64 + tt * 16 + (lane & 15)];
            uint4 bu = make_uint4(0, 0, 0, 0);
            if (lane < 16) {
                bu.x = pack2(p.x, p.y);
                bu.y = pack2(p.z, p.w);
            }
            const f32x4v acc = __builtin_amdgcn_mfma_f32_16x16x32_bf16(
                afrag, __builtin_bit_cast(bf16x8, bu), (f32x4v)0.0f, 0, 0, 0);
            const int j = w * 1024 + g * 64 + tt * 16 + (lane & 15);
#pragma unroll
            for (int r = 0; r < 4; ++r) {
                if (acc[r] <= Tr[r]) {
                    const int q = (lane >> 4) * 4 + r;
                    const int slot = atomicAdd(&scnt[q], 1);
                    if (slot < CAPM) surv[q][slot] = (unsigned)j;
                }
            }
        }
    }
    __syncthreads();

    // ---- merge: exact-f32 rescoring + rank-select; wave w -> queries 2w,2w+1
#pragma unroll
    for (int k = 0; k < 2; ++k) {
        const int q = w * 2 + k;
        const int n = min(scnt[q], CAPM);
        const float4 qq = pos4[qbase + q];
        const float qxE = rfl(-2.0f * qq.x);
        const float qyE = rfl(-2.0f * qq.y);
        const float qzE = rfl(-2.0f * qq.z);
        unsigned long long kk[4];
        unsigned jj[4];
#pragma unroll
        for (int e = 0; e < 4; ++e) {
            const int idx = lane + e * 64;
            kk[e] = ~0ull;
            jj[e] = 0;
            if (idx < n) {
                jj[e] = surv[q][idx];
                const float4 p = pos4[jj[e]];
                const float s = fmaf(qxE, p.x, fmaf(qyE, p.y, fmaf(qzE, p.z, p.w)));
                kk[e] = ((unsigned long long)sortkey(s) << 32) | jj[e];
            }
            keybuf[w][idx < CAPM ? idx : 0] = (idx < n) ? kk[e] : keybuf[w][0];
        }
        // ensure all lanes' keys visible within the wave
        asm volatile("s_waitcnt lgkmcnt(0)" ::: "memory");
        __builtin_amdgcn_sched_barrier(0);
        int rr[4] = {0, 0, 0, 0};
        for (int e = 0; e < n; ++e) {
            const unsigned long long ke = keybuf[w][e];   // LDS broadcast
#pragma unroll
            for (int m = 0; m < 4; ++m) rr[m] += (ke < kk[m]) ? 1 : 0;
        }
#pragma unroll
        for (int e = 0; e < 4; ++e) {
            if (lane + e * 64 < n && rr[e] < KNN)
                idx_out[(qbase + q) * KNN + rr[e]] = (int)jj[e];
        }
    }
}

// ---------------------------------------------------------------------------
// conv_fused (unchanged from passing R16): h_ij = relu(v_j - u_i);
// GEMM2 MFMA + max-aggregate + relu; VNEXT epilogue computes next layer's v.
// ---------------------------------------------------------------------------
template <int CMID, int COUT, int WM, int WN, int VNEXT>
__global__ __launch_bounds__(256) void conv_fused(
    const unsigned short* __restrict__ v, const float* __restrict__ pos,
    const int* __restrict__ idx,
    const float* __restrict__ WaRel,            // 3 x CMID (rows CIN..CIN+2 of Wa)
    const uint4* __restrict__ fB, const float* __restrict__ bb,
    const float* __restrict__ Wnext, const float* __restrict__ bnext,
    float* __restrict__ out, unsigned short* __restrict__ vout)
{
    constexpr int PB  = 8, M = 128;
    constexpr int KP2 = CMID + 8;
    constexpr int KS2 = CMID / 32;
    constexpr int NT  = COUT / 16;
    constexpr int NTW = NT / WN;
    constexpr int MFW = (M / 16) / WM;

    __shared__ int nbr[M];
    __shared__ float ubuf[PB][CMID];
    __shared__ __align__(16) unsigned short hbuf[M * KP2];

    const int tid  = threadIdx.x;
    const int lane = tid & 63;
    const int w    = tid >> 6;
    const int wm   = w / WN, wn = w % WN;
    const int i0   = blockIdx.x * PB;

    if (tid < M) nbr[tid] = idx[i0 * KNN + tid];
    for (int e = tid; e < PB * CMID; e += 256) {
        const int pt = e / CMID, c = e % CMID;
        float u = pos[(i0 + pt) * 3 + 0] * WaRel[c];
        u = fmaf(pos[(i0 + pt) * 3 + 1], WaRel[CMID + c], u);
        u = fmaf(pos[(i0 + pt) * 3 + 2], WaRel[2 * CMID + c], u);
        ubuf[pt][c] = u;
    }
    __syncthreads();

    {
        const int row = tid >> 1, hh = tid & 1;
        const int j = nbr[row], pt = row >> 4;
        const int cb = hh * (CMID / 2);
#pragma unroll
        for (int cc = 0; cc < CMID / 2; cc += 8) {
            const uint4 vv = *reinterpret_cast<const uint4*>(v + j * CMID + cb + cc);
            const unsigned dw[4] = {vv.x, vv.y, vv.z, vv.w};
            unsigned o[4];
#pragma unroll
            for (int d2 = 0; d2 < 4; ++d2) {
                const int c = cb + cc + d2 * 2;
                const float flo = __uint_as_float(dw[d2] << 16);
                const float fhi = __uint_as_float(dw[d2] & 0xffff0000u);
                const float rlo = fmaxf(flo - ubuf[pt][c],     0.0f);
                const float rhi = fmaxf(fhi - ubuf[pt][c + 1], 0.0f);
                o[d2] = pack2(rlo, rhi);
            }
            *reinterpret_cast<uint4*>(&hbuf[row * KP2 + cb + cc]) =
                make_uint4(o[0], o[1], o[2], o[3]);
        }
    }
    __syncthreads();

    float outv[MFW][NTW];
    {
        uint4 b2[KS2][NTW];
#pragma unroll
        for (int ks = 0; ks < KS2; ++ks)
#pragma unroll
            for (int nt = 0; nt < NTW; ++nt)
                b2[ks][nt] = fB[(ks * NT + wn * NTW + nt) * 64 + lane];

        f32x4v acc2[MFW][NTW];
#pragma unroll
        for (int mf = 0; mf < MFW; ++mf)
#pragma unroll
            for (int nt = 0; nt < NTW; ++nt) acc2[mf][nt] = (f32x4v)0.0f;

#pragma unroll
        for (int mf = 0; mf < MFW; ++mf) {
            bf16x8 a[KS2];
#pragma unroll
            for (int ks = 0; ks < KS2; ++ks)
                a[ks] = *reinterpret_cast<const bf16x8*>(
                    &hbuf[((wm * MFW + mf) * 16 + (lane & 15)) * KP2 + ks * 32 + (lane >> 4) * 8]);
#pragma unroll
            for (int nt = 0; nt < NTW; ++nt)
#pragma unroll
                for (int ks = 0; ks < KS2; ++ks)
                    acc2[mf][nt] = __builtin_amdgcn_mfma_f32_16x16x32_bf16(
                        a[ks], __builtin_bit_cast(bf16x8, b2[ks][nt]), acc2[mf][nt], 0, 0, 0);
        }

        float bbv[NTW];
#pragma unroll
        for (int nt = 0; nt < NTW; ++nt) bbv[nt] = bb[(wn * NTW + nt) * 16 + (lane & 15)];

#pragma unroll
        for (int mf = 0; mf < MFW; ++mf)
#pragma unroll
            for (int nt = 0; nt < NTW; ++nt) {
                const f32x4v t = acc2[mf][nt];
                float m0 = fmaxf(fmaxf(t[0], t[1]), fmaxf(t[2], t[3]));
                m0 = fmaxf(m0, __shfl_xor(m0, 16));
                m0 = fmaxf(m0, __shfl_xor(m0, 32));
                outv[mf][nt] = fmaxf(m0 + bbv[nt], 0.0f);
            }
    }
    __syncthreads();

#pragma unroll
    for (int mf = 0; mf < MFW; ++mf)
#pragma unroll
        for (int nt = 0; nt < NTW; ++nt) {
            if (lane < 16) {
                const int pt = wm * MFW + mf;
                const int c  = (wn * NTW + nt) * 16 + lane;
                out[(i0 + pt) * COUT + c] = outv[mf][nt];
                if constexpr (VNEXT > 0) hbuf[pt * KP2 + c] = f2bf(outv[mf][nt]);
            }
        }

    if constexpr (VNEXT > 0) {
        __syncthreads();
        constexpr int CPT = VNEXT / 32;
        const int pt = tid >> 5;
        const int c0 = (tid & 31) * CPT;
        float acc[CPT];
#pragma unroll
        for (int e = 0; e < CPT; ++e) acc[e] = bnext[c0 + e];
        for (int k = 0; k < COUT; ++k) {
            const float hk = bf2f(hbuf[pt * KP2 + k]);
#pragma unroll
            for (int e = 0; e < CPT; ++e)
                acc[e] = fmaf(hk, Wnext[k * VNEXT + c0 + e], acc[e]);
        }
#pragma unroll
        for (int d = 0; d < 3; ++d) {
            const float pd = pos[(i0 + pt) * 3 + d];
#pragma unroll
            for (int e = 0; e < CPT; ++e)
                acc[e] = fmaf(pd, Wnext[(COUT + d) * VNEXT + c0 + e], acc[e]);
        }
        if constexpr (CPT == 2) {
            *reinterpret_cast<unsigned*>(vout + (i0 + pt) * VNEXT + c0) = pack2(acc[0], acc[1]);
        } else {
            uint2 o;
            o.x = pack2(acc[0], acc[1]);
            o.y = pack2(acc[2], acc[3]);
            *reinterpret_cast<uint2*>(vout + (i0 + pt) * VNEXT + c0) = o;
        }
    }
}

extern "C" void kernel_launch(void* const* d_in, const int* in_sizes, int n_in,
                              void* d_out, int out_size, void* d_ws, size_t ws_size,
                              hipStream_t stream)
{
    const float* pos = (const float*)d_in[0];
    const float* W1a = (const float*)d_in[1];
    const float* b1a = (const float*)d_in[2];
    const float* W1b = (const float*)d_in[3];
    const float* b1b = (const float*)d_in[4];
    const float* W2a = (const float*)d_in[5];
    const float* b2a = (const float*)d_in[6];
    const float* W2b = (const float*)d_in[7];
    const float* b2b = (const float*)d_in[8];
    const float* W3a = (const float*)d_in[9];
    const float* b3a = (const float*)d_in[10];
    const float* W3b = (const float*)d_in[11];
    const float* b3b = (const float*)d_in[12];

    float* out = (float*)d_out;
    float* h1 = out;                        // 8192 x 64
    float* h2 = out + N_PTS * 64;           // 8192 x 64
    float* h3 = out + N_PTS * 128;          // 8192 x 128

    // workspace: idx (512K) | Wb frags (48K) | v3 (2MB bf16)
    int*            idx     = (int*)d_ws;
    uint4*          wsFrags = (uint4*)((char*)d_ws + 524288);
    unsigned short* v3      = (unsigned short*)((char*)d_ws + 589824);

    // h3 region (dead until conv3): pos4 (128K) | v1 (1MB) | v2 (1MB)
    float4*         pos4 = (float4*)h3;
    unsigned short* v1   = (unsigned short*)((char*)h3 + 131072);
    unsigned short* v2   = (unsigned short*)((char*)h3 + 1179648);

    prep_all<<<112, 256, 0, stream>>>(pos, pos4, v1, W1a, b1a, W1b, W2b, W3b, wsFrags);
    knn_kernel<<<N_PTS / QB, 512, 0, stream>>>(pos4, idx);

    const uint4* fW1b = wsFrags + 0 * 64;
    const uint4* fW2b = wsFrags + 8 * 64;
    const uint4* fW3b = wsFrags + 16 * 64;

    conv_fused<64, 64, 4, 1, 64><<<N_PTS / 8, 256, 0, stream>>>(
        v1, pos, idx, W1a + 3 * 64, fW1b, b1b, W2a, b2a, h1, v2);
    conv_fused<64, 64, 4, 1, 128><<<N_PTS / 8, 256, 0, stream>>>(
        v2, pos, idx, W2a + 64 * 64, fW2b, b2b, W3a, b3a, h2, v3);
    conv_fused<128, 128, 2, 2, 0><<<N_PTS / 8, 256, 0, stream>>>(
        v3, pos, idx, W3a + 64 * 128, fW3b, b3b, nullptr, nullptr, h3, nullptr);
}